// Round 16
// baseline (343.743 us; speedup 1.0000x reference)
//
#include <hip/hip_runtime.h>
#include <math.h>
#include <stdint.h>

#define HP 256
#define PTS 32                // points per workgroup: 2 chunks x 16
#define ROWS 128              // per chunk: 16 points x 8 channels
#define PSTR 264              // halves per A row (proven 0-conflict)
#define NLAYER 6
#define WT_ELEMS (6*256*256)  // fp16 weights, wave-packed
#define PREP_TILES 96

typedef _Float16 half8 __attribute__((ext_vector_type(8)));
typedef _Float16 half2v __attribute__((ext_vector_type(2)));
typedef float  float16v __attribute__((ext_vector_type(16)));

#define C_WI 0
#define C_BI 768
#define C_BH 1024
#define C_WO 2560
#define C_TOT 3584

__device__ __forceinline__ float fast_tanh(float x) {
    float e = __expf(2.0f * x);
    return 1.0f - __fdividef(2.0f, e + 1.0f);
}

__device__ __forceinline__ float16v zero16() {
    float16v z;
    #pragma unroll
    for (int i = 0; i < 16; ++i) z[i] = 0.0f;
    return z;
}

// A-row for (local point P in 0..15, channel c in 0..7): shuffle-free epilogue mapping.
__device__ __forceinline__ int arow(int P, int c) {
    return 32*(P >> 2) + 16*((P >> 1) & 1) + 4*(P & 1) + 8*(c >> 2) + (c & 3);
}

#define MFMA16(A,B,Cc) __builtin_amdgcn_mfma_f32_32x32x16_f16((A),(B),(Cc),0,0,0)

// ---------------- prep: LDS-transpose pack (coalesced both directions) ----------------
__global__ void prep_kernel(const float* __restrict__ W_in, const float* __restrict__ b_in,
                            const float* __restrict__ W_h,  const float* __restrict__ b_h,
                            const float* __restrict__ W_out, void* __restrict__ wsv)
{
    _Float16* wt = (_Float16*)wsv;
    float* cf = (float*)((char*)wsv + (size_t)WT_ELEMS * 2);
    _Float16* cfh = (_Float16*)(cf + C_TOT);    // Wo_t[4][256]

    const int tid = threadIdx.x;
    const int bid = blockIdx.x;

    if (bid < PREP_TILES) {
        __shared__ _Float16 tile[64 * 65];
        int l  = bid / 16;
        int ka = (bid % 16) >> 2;
        int na = bid & 3;
        int k0 = 64 * ka, n0 = 64 * na;
        #pragma unroll
        for (int pass = 0; pass < 16; ++pass) {
            int idx = pass * 256 + tid;
            int kl = idx >> 6, nl = idx & 63;
            int k = k0 + kl, n = n0 + nl;
            float v = (k < 250 && n < 250) ? W_h[(l*250 + k)*250 + n] : 0.0f;
            tile[kl * 65 + nl] = (_Float16)v;
        }
        __syncthreads();
        #pragma unroll
        for (int b = 0; b < 2; ++b) {
            int slot = tid * 2 + b;
            int lo5  = slot & 31;
            int st_l = (slot >> 5) & 1;
            int hi5  = (slot >> 6) & 1;
            int s_l  = slot >> 7;
            int nl = st_l * 32 + lo5;
            half8 hv;
            #pragma unroll
            for (int j = 0; j < 8; ++j)
                hv[j] = tile[(s_l * 16 + hi5 * 8 + j) * 65 + nl];
            int s    = ka * 4 + s_l;
            int st   = na * 2 + st_l;
            int lane = hi5 * 32 + lo5;
            size_t dst = ((size_t)l << 16) | (s << 12) | (st << 9) | (lane << 3);
            *(half8*)(wt + dst) = hv;
        }
    } else {
        int i0 = (bid - PREP_TILES) * blockDim.x + tid;
        int stride = 8 * blockDim.x;
        for (int i = i0; i < C_TOT; i += stride) {
            float v = 0.0f;
            if (i < C_BI) { int r = i >> 8, j = i & 255; if (j < 250) v = W_in[r*250 + j]; }
            else if (i < C_BH) { int j = i - C_BI; if (j < 250) v = b_in[j]; }
            else if (i < C_WO) { int idx = i - C_BH; int l = idx >> 8, j = idx & 255; if (j < 250) v = b_h[l*250 + j]; }
            else { int idx = i - C_WO; int k = idx >> 2, o = idx & 3; if (k < 250) v = W_out[k*4 + o]; }
            cf[i] = v;
        }
        for (int i = i0; i < 1024; i += stride) {
            int o = i >> 8, k = i & 255;
            cfh[i] = (_Float16)(k < 250 ? W_out[k*4 + o] : 0.0f);
        }
    }
}

// PHASE: full K-loop for chunk KPL layer LK (rd13's proven body, fills KM[4])
// interleaved 2:1 with epilogue of the OTHER chunk EPL layer LE (consumes EM[4]).
#define PHASE(DOK, KPL, LK, KM, DOE, EPL, LE, EM) do {                          \
  const _Float16* ph_ = wt;                                                      \
  half8 Bq_[4], a0_[4], a1_[4];                                                  \
  if (DOK) {                                                                     \
    ph_ = wt + (((size_t)(LK)) << 16) + ((size_t)w << 9) + (size_t)lane * 8;     \
    _Pragma("unroll") for (int i_ = 0; i_ < 4; ++i_)                             \
      Bq_[i_] = *(const half8*)(ph_ + 4096*i_);                                  \
    _Pragma("unroll") for (int rt_ = 0; rt_ < 4; ++rt_) {                        \
      KM[rt_] = zero16();                                                        \
      a0_[rt_] = *(const half8*)&KPL[abase + 32*rt_*PSTR];                       \
      a1_[rt_] = *(const half8*)&KPL[abase + 32*rt_*PSTR + 16];                  \
    }                                                                            \
  }                                                                              \
  float cc_ = 0.f, bb_ = 0.f;                                                    \
  if (DOE) {                                                                     \
    cc_ = 10.0f * act[(LE) + 1];                                                 \
    bb_ = cf[C_BH + ((LE) << 8) + n0];                                           \
  }                                                                              \
  _Pragma("unroll")                                                              \
  for (int ch_ = 0; ch_ < 8; ++ch_) {                                            \
    if (DOK) {                                                                   \
      _Pragma("unroll")                                                          \
      for (int u_ = 0; u_ < 2; ++u_) {                                           \
        const int s_ = 2*ch_ + u_;                                               \
        half8 b_ = Bq_[s_ & 3];                                                  \
        if (s_ < 12) Bq_[s_ & 3] = *(const half8*)(ph_ + 4096*(s_ + 4));         \
        half8 cur_[4];                                                           \
        _Pragma("unroll") for (int rt_ = 0; rt_ < 4; ++rt_) {                    \
          cur_[rt_] = a0_[rt_]; a0_[rt_] = a1_[rt_];                             \
        }                                                                        \
        if (s_ < 14) {                                                           \
          _Pragma("unroll") for (int rt_ = 0; rt_ < 4; ++rt_)                    \
            a1_[rt_] = *(const half8*)&KPL[abase + 32*rt_*PSTR + 16*(s_ + 2)];   \
        }                                                                        \
        _Pragma("unroll") for (int rt_ = 0; rt_ < 4; ++rt_)                      \
          KM[rt_] = MFMA16(cur_[rt_], b_, KM[rt_]);                              \
      }                                                                          \
    }                                                                            \
    if (DOE) {                                                                   \
      const int rt_ = ch_ >> 1, pp_ = ch_ & 1;                                   \
      float16v mv_ = EM[rt_];                                                    \
      float z_   = mv_[8*pp_+0] + bb_;                                           \
      float zx_  = mv_[8*pp_+1];                                                 \
      float zy_  = mv_[8*pp_+2];                                                 \
      float zt_  = mv_[8*pp_+3];                                                 \
      float zxx_ = mv_[8*pp_+4];                                                 \
      float zyy_ = mv_[8*pp_+5];                                                 \
      float zxy_ = mv_[8*pp_+6];                                                 \
      float y_   = fast_tanh(cc_ * z_);                                          \
      float sh_  = 1.0f - y_*y_;                                                 \
      float cs_  = cc_ * sh_;                                                    \
      float m2_  = -2.0f * cc_ * cs_ * y_;                                       \
      int r0_ = (32*rt_ + 16*pp_ + 4*hi5) * PSTR + n0;                           \
      EPL[r0_ + 0*PSTR] = (_Float16)y_;                                          \
      EPL[r0_ + 1*PSTR] = (_Float16)(cs_*zx_);                                   \
      EPL[r0_ + 2*PSTR] = (_Float16)(cs_*zy_);                                   \
      EPL[r0_ + 3*PSTR] = (_Float16)(cs_*zt_);                                   \
      int r1_ = r0_ + 8*PSTR;                                                    \
      EPL[r1_ + 0*PSTR] = (_Float16)(cs_*zxx_ + m2_*zx_*zx_);                    \
      EPL[r1_ + 1*PSTR] = (_Float16)(cs_*zyy_ + m2_*zy_*zy_);                    \
      EPL[r1_ + 2*PSTR] = (_Float16)(cs_*zxy_ + m2_*zx_*zy_);                    \
      EPL[r1_ + 3*PSTR] = (_Float16)0.0f;                                        \
    }                                                                            \
  }                                                                              \
} while (0)

// ---------------- fused PINN kernel ----------------
// 512 threads = 8 waves; wave w owns col strip 32*w for all 128 rows of the
// active chunk. Two chunks (A: pts 0-15, B: pts 16-31) in separate LDS planes;
// every phase = one chunk's full K-loop + the other chunk's epilogue.
__launch_bounds__(512, 2)
__global__ void pinn_mfma(const float* __restrict__ xg, const float* __restrict__ yg,
                          const float* __restrict__ tg, const void* __restrict__ wsv,
                          const float* __restrict__ b_out, const float* __restrict__ act,
                          float* __restrict__ out, int N)
{
    __shared__ _Float16 AhA[ROWS * PSTR];
    __shared__ _Float16 AhB[ROWS * PSTR];
    __shared__ float zo[PTS][28];

    const _Float16* __restrict__ wt = (const _Float16*)wsv;
    const float* __restrict__ cf = (const float*)((const char*)wsv + (size_t)WT_ELEMS * 2);
    const _Float16* __restrict__ cfh = (const _Float16*)(cf + C_TOT);

    const int tid  = threadIdx.x;
    const int lane = tid & 63;
    const int w    = tid >> 6;
    const int lo5  = lane & 31;
    const int hi5  = lane >> 5;
    const int n0   = 32*w + lo5;
    const int abase = lo5 * PSTR + 8*hi5;

    // ---------- input layer jet: hf picks the chunk; 16 points per thread-half ----------
    {
        int j  = tid & 255;
        int hf = tid >> 8;                    // 0: chunk A, 1: chunk B
        _Float16* pl = hf ? AhB : AhA;
        float wi0 = cf[C_WI + j], wi1 = cf[C_WI + 256 + j], wi2 = cf[C_WI + 512 + j];
        float biv = cf[C_BI + j];
        float c0 = 10.0f * act[0];
        #pragma unroll
        for (int p = 0; p < 16; ++p) {
            int gp = blockIdx.x * PTS + 16*hf + p;
            gp = gp < N ? gp : N - 1;
            float px = xg[gp], py = yg[gp], pt = tg[gp];
            float z = px*wi0 + py*wi1 + pt*wi2 + biv;
            float y = fast_tanh(c0 * z);
            float s = 1.0f - y*y;
            float cs = c0 * s;
            float m2 = -2.0f * c0 * cs * y;
            float o[8];
            o[0] = y;           o[1] = cs*wi0;      o[2] = cs*wi1;      o[3] = cs*wi2;
            o[4] = m2*wi0*wi0;  o[5] = m2*wi1*wi1;  o[6] = m2*wi0*wi1;  o[7] = 0.0f;
            #pragma unroll
            for (int c = 0; c < 8; ++c)
                pl[arow(p, c)*PSTR + j] = (_Float16)o[c];
        }
    }

    float16v mA[4], mB[4];

    __syncthreads();
    PHASE(1, AhA, 0, mA,  0, AhA, 0, mA);           // K(A,0)
    __syncthreads();

    for (int L = 0; L < NLAYER; ++L) {
        PHASE(1, AhB, L, mB,  1, AhA, L, mA);       // K(B,L) + E(A,L)
        __syncthreads();
        if (L + 1 < NLAYER) {
            PHASE(1, AhA, L+1, mA,  1, AhB, L, mB); // K(A,L+1) + E(B,L)
        } else {
            PHASE(0, AhA, 0, mA,  1, AhB, L, mB);   // E(B,5) tail
        }
        __syncthreads();
    }

    // ---------- output layer: 32 points x 28 dots, 512 threads loop ----------
    for (int job = tid; job < PTS * 28; job += 512) {
        int p = job / 28, idx = job % 28;
        int c = idx >> 2, o = idx & 3;
        const _Float16* pl = (p < 16) ? AhA : AhB;
        const _Float16* rh = &pl[arow(p & 15, c) * PSTR];
        const _Float16* wo = cfh + (o << 8);
        float s = 0.0f;
        for (int kq = 0; kq < HP/8; ++kq) {
            half8 h  = *(const half8*)(rh + 8*kq);
            half8 ww = *(const half8*)(wo + 8*kq);
#if __has_builtin(__builtin_amdgcn_fdot2)
            #pragma unroll
            for (int j = 0; j < 4; ++j) {
                half2v ha = { h[2*j], h[2*j+1] };
                half2v wa = { ww[2*j], ww[2*j+1] };
                s = __builtin_amdgcn_fdot2(ha, wa, s, false);
            }
#else
            #pragma unroll
            for (int j = 0; j < 8; ++j) s += (float)h[j] * (float)ww[j];
#endif
        }
        zo[p][idx] = s;
    }
    __syncthreads();

    // ---------- heads + PDE residuals ----------
    if (tid < PTS) {
        int gp = blockIdx.x * PTS + tid;
        if (gp < N) {
            float zc[7][4];
            #pragma unroll
            for (int c = 0; c < 7; ++c)
                #pragma unroll
                for (int o = 0; o < 4; ++o)
                    zc[c][o] = zo[tid][c*4 + o] + (c == 0 ? b_out[o] : 0.0f);

            float u  = zc[0][0], vv = zc[0][1];
            float u_x = zc[1][0], u_y = zc[2][0], u_t = zc[3][0];
            float u_xx = zc[4][0], u_yy = zc[5][0];
            float v_x = zc[1][1], v_y = zc[2][1], v_t = zc[3][1];
            float v_xx = zc[4][1], v_yy = zc[5][1];

            float ep  = expf(zc[0][2]);
            float p_x = ep * zc[1][2], p_y = ep * zc[2][2];

            float a   = 1.0f / (1.0f + expf(-zc[0][3]));
            float sp  = a * (1.0f - a);
            float spp = sp * (1.0f - 2.0f*a);
            float z1a = zc[1][3], z2a = zc[2][3];
            float a_x = sp * z1a, a_y = sp * z2a, a_t = sp * zc[3][3];
            float a_xx = spp*z1a*z1a + sp*zc[4][3];
            float a_yy = spp*z2a*z2a + sp*zc[5][3];
            float a_xy = spp*z1a*z2a + sp*zc[6][3];

            float mu_x = -9.0f*a_x, mu_y = -9.0f*a_y;
            float mu   = 10.0f - 9.0f*a;
            float rr   = 1.0f - 0.9f*a;
            float g  = sqrtf(a_x*a_x + a_y*a_y + 2.220446049250313e-16f);
            float g3 = g*g*g;
            float curv = -((a_xx + a_yy)/g
                         - (a_x*a_x*a_xx + a_y*a_y*a_yy + 2.0f*a_x*a_y*a_xy)/g3);
            float one_Re   = mu   * 0.002f;
            float one_Re_x = mu_x * 0.002f;
            float one_Re_y = mu_y * 0.002f;

            float PDE_m = u_x + v_y;
            float PDE_a = a_t + u*a_x + vv*a_y;
            float PDE_u = (u_t + u*u_x + vv*u_y)*rr + p_x - 0.049f*curv*a_x
                        - one_Re*(u_xx + u_yy) - 2.0f*one_Re_x*u_x - one_Re_y*(u_y + v_x);
            float PDE_v = (v_t + u*v_x + vv*v_y)*rr + p_y - 0.049f*curv*a_y
                        - one_Re*(v_xx + v_yy) - rr*0.49f
                        - 2.0f*one_Re_y*v_y - one_Re_x*(u_y + v_x);

            out[0*N + gp] = PDE_m;
            out[1*N + gp] = PDE_u;
            out[2*N + gp] = PDE_v;
            out[3*N + gp] = PDE_a;
        }
    }
}

extern "C" void kernel_launch(void* const* d_in, const int* in_sizes, int n_in,
                              void* d_out, int out_size, void* d_ws, size_t ws_size,
                              hipStream_t stream)
{
    const float* x     = (const float*)d_in[0];
    const float* y     = (const float*)d_in[1];
    const float* t     = (const float*)d_in[2];
    const float* W_in  = (const float*)d_in[3];
    const float* b_in  = (const float*)d_in[4];
    const float* W_h   = (const float*)d_in[5];
    const float* b_h   = (const float*)d_in[6];
    const float* W_out = (const float*)d_in[7];
    const float* b_out = (const float*)d_in[8];
    const float* act   = (const float*)d_in[9];
    float* out = (float*)d_out;
    int N = in_sizes[0];

    hipLaunchKernelGGL(prep_kernel, dim3(PREP_TILES + 8), dim3(256), 0, stream,
                       W_in, b_in, W_h, b_h, W_out, d_ws);
    int nb = (N + PTS - 1) / PTS;
    hipLaunchKernelGGL(pinn_mfma, dim3(nb), dim3(512), 0, stream,
                       x, y, t, d_ws, b_out, act, out, N);
}

// Round 17
// 318.904 us; speedup vs baseline: 1.0779x; 1.0779x over previous
//
#include <hip/hip_runtime.h>
#include <math.h>
#include <stdint.h>

#define HP 256
#define PTS 16                // points per workgroup
#define ROWS 128              // 16 points x 8 channels (ch7 dummy)
#define PSTR 264              // halves per A row (dw-stride 132 == 4 mod 32 -> 0-conflict, measured)
#define NLAYER 6
#define WT_ELEMS (6*256*256)  // fp16 weights, wave-packed
#define PREP_TILES 96         // 6 L x 4 ka x 4 na

typedef _Float16 half8 __attribute__((ext_vector_type(8)));
typedef _Float16 half2v __attribute__((ext_vector_type(2)));
typedef float  float16v __attribute__((ext_vector_type(16)));

// f32 extras section (float offsets; section starts at byte WT_ELEMS*2)
#define C_WI 0                // [3][256]
#define C_BI 768              // [256]
#define C_BH 1024             // [6][256]
#define C_WO 2560             // [256][4]
#define C_TOT 3584
// fp16 Wo_t[4][256] appended after cf

__device__ __forceinline__ float fast_tanh(float x) {
    float e = __expf(2.0f * x);
    return 1.0f - __fdividef(2.0f, e + 1.0f);
}

__device__ __forceinline__ float16v zero16() {
    float16v z;
    #pragma unroll
    for (int i = 0; i < 16; ++i) z[i] = 0.0f;
    return z;
}

// A-row for (point P in 0..15, channel c in 0..7): in the 32x32 MFMA C-layout
// (row=(reg&3)+8*(reg>>2)+4*hi5) each lane's reg quads 2pp/2pp+1 hold ch0-3 /
// ch4-7 of point 4*tile+2pp+hi5 -> shuffle-free, divergence-free epilogue.
__device__ __forceinline__ int arow(int P, int c) {
    return 32*(P >> 2) + 16*((P >> 1) & 1) + 4*(P & 1) + 8*(c >> 2) + (c & 3);
}

#define MFMA16(A,B,Cc) __builtin_amdgcn_mfma_f32_32x32x16_f16((A),(B),(Cc),0,0,0)

// ---------------- prep: LDS-transpose pack (coalesced both directions) ----------------
// wq[L][s][strip][lane][j]: lane=(hi5<<5)|lo5 holds B[n=32*strip+lo5][k=16*s+8*hi5+j].
__global__ void prep_kernel(const float* __restrict__ W_in, const float* __restrict__ b_in,
                            const float* __restrict__ W_h,  const float* __restrict__ b_h,
                            const float* __restrict__ W_out, void* __restrict__ wsv)
{
    _Float16* wt = (_Float16*)wsv;
    float* cf = (float*)((char*)wsv + (size_t)WT_ELEMS * 2);
    _Float16* cfh = (_Float16*)(cf + C_TOT);    // Wo_t[4][256]

    const int tid = threadIdx.x;
    const int bid = blockIdx.x;

    if (bid < PREP_TILES) {
        __shared__ _Float16 tile[64 * 65];
        int l  = bid / 16;
        int ka = (bid % 16) >> 2;
        int na = bid & 3;
        int k0 = 64 * ka, n0 = 64 * na;
        #pragma unroll
        for (int pass = 0; pass < 16; ++pass) {
            int idx = pass * 256 + tid;
            int kl = idx >> 6, nl = idx & 63;
            int k = k0 + kl, n = n0 + nl;
            float v = (k < 250 && n < 250) ? W_h[(l*250 + k)*250 + n] : 0.0f;
            tile[kl * 65 + nl] = (_Float16)v;
        }
        __syncthreads();
        #pragma unroll
        for (int b = 0; b < 2; ++b) {
            int slot = tid * 2 + b;
            int lo5  = slot & 31;
            int st_l = (slot >> 5) & 1;
            int hi5  = (slot >> 6) & 1;
            int s_l  = slot >> 7;
            int nl = st_l * 32 + lo5;
            half8 hv;
            #pragma unroll
            for (int j = 0; j < 8; ++j)
                hv[j] = tile[(s_l * 16 + hi5 * 8 + j) * 65 + nl];
            int s    = ka * 4 + s_l;
            int st   = na * 2 + st_l;
            int lane = hi5 * 32 + lo5;
            size_t dst = ((size_t)l << 16) | (s << 12) | (st << 9) | (lane << 3);
            *(half8*)(wt + dst) = hv;
        }
    } else {
        int i0 = (bid - PREP_TILES) * blockDim.x + tid;
        int stride = 8 * blockDim.x;
        for (int i = i0; i < C_TOT; i += stride) {
            float v = 0.0f;
            if (i < C_BI) { int r = i >> 8, j = i & 255; if (j < 250) v = W_in[r*250 + j]; }
            else if (i < C_BH) { int j = i - C_BI; if (j < 250) v = b_in[j]; }
            else if (i < C_WO) { int idx = i - C_BH; int l = idx >> 8, j = idx & 255; if (j < 250) v = b_h[l*250 + j]; }
            else { int idx = i - C_WO; int k = idx >> 2, o = idx & 3; if (k < 250) v = W_out[k*4 + o]; }
            cf[i] = v;
        }
        for (int i = i0; i < 1024; i += stride) {
            int o = i >> 8, k = i & 255;
            cfh[i] = (_Float16)(k < 250 ? W_out[k*4 + o] : 0.0f);
        }
    }
}

// ---------------- fused PINN kernel (rd13 anchor) ----------------
// 512 threads = 8 waves. Wave w owns col strip 32*w..+31 for ALL 128 rows
// (4 row tiles -> 4 accumulators, 64 AGPR). One coalesced 1KB B load per k-step
// feeds 4 MFMAs. Weights streamed once per 16 points. 2 blocks/CU give free
// cross-block MFMA/VALU phase overlap (beat every engineered alternative).
__launch_bounds__(512, 4)
__global__ void pinn_mfma(const float* __restrict__ xg, const float* __restrict__ yg,
                          const float* __restrict__ tg, const void* __restrict__ wsv,
                          const float* __restrict__ b_out, const float* __restrict__ act,
                          float* __restrict__ out, int N)
{
    __shared__ _Float16 Ah[ROWS * PSTR];
    __shared__ float zo[PTS][28];

    const _Float16* __restrict__ wt = (const _Float16*)wsv;
    const float* __restrict__ cf = (const float*)((const char*)wsv + (size_t)WT_ELEMS * 2);
    const _Float16* __restrict__ cfh = (const _Float16*)(cf + C_TOT);

    const int tid  = threadIdx.x;
    const int lane = tid & 63;
    const int w    = tid >> 6;        // wave id: col strip 32*w
    const int lo5  = lane & 31;
    const int hi5  = lane >> 5;
    const int n0   = 32*w + lo5;      // this lane's output neuron

    // ---------- input layer jet: halves of the block split the 16 points ----------
    {
        int j   = tid & 255;          // neuron
        int hf  = tid >> 8;           // 0: points 0-7, 1: points 8-15
        float wi0 = cf[C_WI + j], wi1 = cf[C_WI + 256 + j], wi2 = cf[C_WI + 512 + j];
        float biv = cf[C_BI + j];
        float c0 = 10.0f * act[0];
        #pragma unroll
        for (int p8 = 0; p8 < 8; ++p8) {
            int p  = 8*hf + p8;
            int gp = blockIdx.x * PTS + p;
            gp = gp < N ? gp : N - 1;
            float px = xg[gp], py = yg[gp], pt = tg[gp];
            float z = px*wi0 + py*wi1 + pt*wi2 + biv;
            float y = fast_tanh(c0 * z);
            float s = 1.0f - y*y;
            float cs = c0 * s;
            float m2 = -2.0f * c0 * cs * y;
            float o[8];
            o[0] = y;           o[1] = cs*wi0;      o[2] = cs*wi1;      o[3] = cs*wi2;
            o[4] = m2*wi0*wi0;  o[5] = m2*wi1*wi1;  o[6] = m2*wi0*wi1;  o[7] = 0.0f;
            #pragma unroll
            for (int c = 0; c < 8; ++c)       // ch7 zero row written ONCE here;
                Ah[arow(p, c)*PSTR + j] = (_Float16)o[c];  // epilogues skip it
        }
    }

    // ---------- hidden layers ----------
    for (int L = 0; L < NLAYER; ++L) {
        float cc = 10.0f * act[L + 1];
        // wave-packed weights: step s at ph + 4096*s (1KB contiguous per wave)
        const _Float16* __restrict__ ph = wt + ((size_t)L << 16) + ((size_t)w << 9)
                                             + (size_t)lane * 8;

        half8 Bq[4];
        #pragma unroll
        for (int i = 0; i < 4; ++i)                   // B preload before barrier (read-only)
            Bq[i] = *(const half8*)(ph + 4096*i);

        float16v m[4];
        #pragma unroll
        for (int rt = 0; rt < 4; ++rt) m[rt] = zero16();

        __syncthreads();                              // A plane stable

        const int abase = lo5 * PSTR + 8*hi5;
        half8 a0[4], a1[4];
        #pragma unroll
        for (int rt = 0; rt < 4; ++rt) {
            a0[rt] = *(const half8*)&Ah[abase + 32*rt*PSTR];
            a1[rt] = *(const half8*)&Ah[abase + 32*rt*PSTR + 16];
        }

        #pragma unroll
        for (int s = 0; s < 16; ++s) {
            half8 b = Bq[s & 3];
            if (s < 12)                               // refill distance-4 B queue
                Bq[s & 3] = *(const half8*)(ph + 4096*(s + 4));
            half8 cur[4];
            #pragma unroll
            for (int rt = 0; rt < 4; ++rt) { cur[rt] = a0[rt]; a0[rt] = a1[rt]; }
            if (s < 14) {
                #pragma unroll
                for (int rt = 0; rt < 4; ++rt)        // refill distance-2 A queue
                    a1[rt] = *(const half8*)&Ah[abase + 32*rt*PSTR + 16*(s + 2)];
            }
            #pragma unroll
            for (int rt = 0; rt < 4; ++rt)
                m[rt] = MFMA16(cur[rt], b, m[rt]);
        }

        __syncthreads();                              // all reads done before overwrite

        float bb = cf[C_BH + (L << 8) + n0];          // hidden bias (per output neuron)

        // ---- epilogue: shuffle-free, divergence-free; 4 row tiles x 2 points ----
        #pragma unroll
        for (int rt = 0; rt < 4; ++rt) {
            float16v mv = m[rt];
            #pragma unroll
            for (int pp = 0; pp < 2; ++pp) {
                float z   = mv[8*pp+0] + bb;
                float zx  = mv[8*pp+1];
                float zy  = mv[8*pp+2];
                float zt  = mv[8*pp+3];
                float zxx = mv[8*pp+4];
                float zyy = mv[8*pp+5];
                float zxy = mv[8*pp+6];
                float y   = fast_tanh(cc * z);
                float sh  = 1.0f - y*y;
                float cs  = cc * sh;
                float m2c = -2.0f * cc * cs * y;
                int r0 = (32*rt + 16*pp + 4*hi5) * PSTR + n0;   // quad 2pp rows (ch0-3)
                Ah[r0 + 0*PSTR] = (_Float16)y;
                Ah[r0 + 1*PSTR] = (_Float16)(cs*zx);
                Ah[r0 + 2*PSTR] = (_Float16)(cs*zy);
                Ah[r0 + 3*PSTR] = (_Float16)(cs*zt);
                int r1 = r0 + 8*PSTR;                            // quad 2pp+1 rows (ch4-6)
                Ah[r1 + 0*PSTR] = (_Float16)(cs*zxx + m2c*zx*zx);
                Ah[r1 + 1*PSTR] = (_Float16)(cs*zyy + m2c*zy*zy);
                Ah[r1 + 2*PSTR] = (_Float16)(cs*zxy + m2c*zx*zy);
                // ch7 row stays zero from init — no store
            }
        }
    }

    // ---------- output layer: 28 dots per point (half8 A + fp16 Wo_t, fdot2) ----------
    __syncthreads();
    if (tid < PTS * 28) {
        int p = tid / 28, idx = tid % 28;
        int c = idx >> 2, o = idx & 3;
        const _Float16* rh = &Ah[arow(p, c) * PSTR];
        const _Float16* wo = cfh + (o << 8);
        float s = 0.0f;
        for (int kq = 0; kq < HP/8; ++kq) {
            half8 h  = *(const half8*)(rh + 8*kq);
            half8 ww = *(const half8*)(wo + 8*kq);
#if __has_builtin(__builtin_amdgcn_fdot2)
            #pragma unroll
            for (int j = 0; j < 4; ++j) {
                half2v ha = { h[2*j], h[2*j+1] };
                half2v wa = { ww[2*j], ww[2*j+1] };
                s = __builtin_amdgcn_fdot2(ha, wa, s, false);
            }
#else
            #pragma unroll
            for (int j = 0; j < 8; ++j) s += (float)h[j] * (float)ww[j];
#endif
        }
        zo[p][idx] = s;
    }
    __syncthreads();

    // ---------- heads + PDE residuals ----------
    if (tid < PTS) {
        int gp = blockIdx.x * PTS + tid;
        if (gp < N) {
            float zc[7][4];
            #pragma unroll
            for (int c = 0; c < 7; ++c)
                #pragma unroll
                for (int o = 0; o < 4; ++o)
                    zc[c][o] = zo[tid][c*4 + o] + (c == 0 ? b_out[o] : 0.0f);

            float u  = zc[0][0], vv = zc[0][1];
            float u_x = zc[1][0], u_y = zc[2][0], u_t = zc[3][0];
            float u_xx = zc[4][0], u_yy = zc[5][0];
            float v_x = zc[1][1], v_y = zc[2][1], v_t = zc[3][1];
            float v_xx = zc[4][1], v_yy = zc[5][1];

            float ep  = expf(zc[0][2]);
            float p_x = ep * zc[1][2], p_y = ep * zc[2][2];

            float a   = 1.0f / (1.0f + expf(-zc[0][3]));
            float sp  = a * (1.0f - a);
            float spp = sp * (1.0f - 2.0f*a);
            float z1a = zc[1][3], z2a = zc[2][3];
            float a_x = sp * z1a, a_y = sp * z2a, a_t = sp * zc[3][3];
            float a_xx = spp*z1a*z1a + sp*zc[4][3];
            float a_yy = spp*z2a*z2a + sp*zc[5][3];
            float a_xy = spp*z1a*z2a + sp*zc[6][3];

            float mu_x = -9.0f*a_x, mu_y = -9.0f*a_y;
            float mu   = 10.0f - 9.0f*a;
            float rr   = 1.0f - 0.9f*a;
            float g  = sqrtf(a_x*a_x + a_y*a_y + 2.220446049250313e-16f);
            float g3 = g*g*g;
            float curv = -((a_xx + a_yy)/g
                         - (a_x*a_x*a_xx + a_y*a_y*a_yy + 2.0f*a_x*a_y*a_xy)/g3);
            float one_Re   = mu   * 0.002f;
            float one_Re_x = mu_x * 0.002f;
            float one_Re_y = mu_y * 0.002f;

            float PDE_m = u_x + v_y;
            float PDE_a = a_t + u*a_x + vv*a_y;
            float PDE_u = (u_t + u*u_x + vv*u_y)*rr + p_x - 0.049f*curv*a_x
                        - one_Re*(u_xx + u_yy) - 2.0f*one_Re_x*u_x - one_Re_y*(u_y + v_x);
            float PDE_v = (v_t + u*v_x + vv*v_y)*rr + p_y - 0.049f*curv*a_y
                        - one_Re*(v_xx + v_yy) - rr*0.49f
                        - 2.0f*one_Re_y*v_y - one_Re_x*(u_y + v_x);

            out[0*N + gp] = PDE_m;
            out[1*N + gp] = PDE_u;
            out[2*N + gp] = PDE_v;
            out[3*N + gp] = PDE_a;
        }
    }
}

extern "C" void kernel_launch(void* const* d_in, const int* in_sizes, int n_in,
                              void* d_out, int out_size, void* d_ws, size_t ws_size,
                              hipStream_t stream)
{
    const float* x     = (const float*)d_in[0];
    const float* y     = (const float*)d_in[1];
    const float* t     = (const float*)d_in[2];
    const float* W_in  = (const float*)d_in[3];
    const float* b_in  = (const float*)d_in[4];
    const float* W_h   = (const float*)d_in[5];
    const float* b_h   = (const float*)d_in[6];
    const float* W_out = (const float*)d_in[7];
    const float* b_out = (const float*)d_in[8];
    const float* act   = (const float*)d_in[9];
    float* out = (float*)d_out;
    int N = in_sizes[0];

    hipLaunchKernelGGL(prep_kernel, dim3(PREP_TILES + 8), dim3(256), 0, stream,
                       W_in, b_in, W_h, b_h, W_out, d_ws);
    int nb = (N + PTS - 1) / PTS;
    hipLaunchKernelGGL(pinn_mfma, dim3(nb), dim3(512), 0, stream,
                       x, y, t, d_ws, b_out, act, out, N);
}